// Round 17
// baseline (400.017 us; speedup 1.0000x reference)
//
#include <hip/hip_runtime.h>
#include <hip/hip_bf16.h>
#include <hip/hip_cooperative_groups.h>
#include <math.h>

namespace cg = cooperative_groups;

#define NFEAT 512
#define NHID 256
#define HEADS 4
#define HDIM 64
#define NCLASS 40
#define NEG_SLOPE 0.2f
#define EPS_Z 1e-16f

#define CSR_BLOCKS 256
#define CSR_THREADS 1024

typedef short bf16x8 __attribute__((ext_vector_type(8)));
typedef float f32x4 __attribute__((ext_vector_type(4)));

__device__ __forceinline__ float lrelu(float x) {
  return x > 0.f ? x : NEG_SLOPE * x;
}

__device__ __forceinline__ ushort f2bf(float f) {
  union { float f; uint u; } c; c.f = f;
  uint u = c.u;
  uint r = u + 0x7FFFu + ((u >> 16) & 1u);
  return (ushort)(r >> 16);
}
__device__ __forceinline__ float bf2f(ushort h) {
  union { uint u; float f; } c; c.u = ((uint)h) << 16;
  return c.f;
}

// packed f32x2 -> bf16x2 (RTNE), gfx950
__device__ __forceinline__ uint cvtpk(float lo, float hi) {
  uint r;
  asm("v_cvt_pk_bf16_f32 %0, %1, %2" : "=v"(r) : "v"(lo), "v"(hi));
  return r;
}

// ---------------- fused CSR construction (cooperative) ----------------
// zero -> count -> 2-level scan -> scatter, one kernel, grid.sync between
// phases. 256 blocks x 1024 threads (2 blocks/CU max -> co-resident).

__global__ __launch_bounds__(1024) void csr_kernel(
    const int* __restrict__ srcv, const int* __restrict__ dstv, int N, int E,
    int* __restrict__ counts, int* __restrict__ row_off, int* __restrict__ cursor,
    int* __restrict__ edge_src, int* __restrict__ bsum) {
  cg::grid_group grid = cg::this_grid();
  const int t = threadIdx.x;
  const int gid = blockIdx.x * blockDim.x + t;
  const int gstride = gridDim.x * blockDim.x;

  // phase 1: zero counts
  for (int i = gid; i < N; i += gstride) counts[i] = 0;
  grid.sync();

  // phase 2: count in-degrees
  for (int i = gid; i < E; i += gstride) atomicAdd(&counts[dstv[i]], 1);
  grid.sync();

  // phase 3a: per-block chunk scan (chunk C <= 1024)
  __shared__ int tmp[CSR_THREADS];
  const int C = (N + gridDim.x - 1) / gridDim.x;   // 196 for N=50000
  const int b0 = blockIdx.x * C;
  int vcnt = 0;
  if (t < C && b0 + t < N) vcnt = counts[b0 + t];
  tmp[t] = vcnt;
  __syncthreads();
  for (int off = 1; off < CSR_THREADS; off <<= 1) {
    int u = (t >= off) ? tmp[t - off] : 0;
    __syncthreads();
    tmp[t] += u;
    __syncthreads();
  }
  if (t == CSR_THREADS - 1) bsum[blockIdx.x] = tmp[t];
  const int excl_t = tmp[t] - vcnt;     // register carries across grid.sync
  grid.sync();

  // phase 3b: block 0 scans the block sums (inclusive)
  if (blockIdx.x == 0) {
    int nb = gridDim.x;
    int vb = (t < nb) ? bsum[t] : 0;
    tmp[t] = vb;
    __syncthreads();
    for (int off = 1; off < CSR_THREADS; off <<= 1) {
      int u = (t >= off) ? tmp[t - off] : 0;
      __syncthreads();
      tmp[t] += u;
      __syncthreads();
    }
    if (t < nb) bsum[t] = tmp[t];
  }
  grid.sync();

  // phase 3c: write row_off + cursor
  const int boff = (blockIdx.x > 0) ? bsum[blockIdx.x - 1] : 0;
  if (t < C && b0 + t < N) {
    int val = excl_t + boff;
    row_off[b0 + t] = val;
    cursor[b0 + t] = val;
  }
  if (gid == 0) row_off[N] = E;
  grid.sync();

  // phase 4: scatter edges into CSR order
  for (int i = gid; i < E; i += gstride) {
    int pos = atomicAdd(&cursor[dstv[i]], 1);
    edge_src[pos] = srcv[i];
  }
}

// ---------------- W1 prep: f32 [512][256] -> frag-major bf16 ----------------

__global__ __launch_bounds__(64) void wprep_kernel(const float* __restrict__ W,
    ushort* __restrict__ Bh) {
  int fb = blockIdx.x;          // ct*16 + ks, 256 blocks
  int ct = fb >> 4, ks = fb & 15;
  int l = threadIdx.x;
  int g = l >> 4, rr = l & 15;
  uint hw[4];
  #pragma unroll
  for (int p = 0; p < 4; ++p) {
    ushort h2v[2];
    #pragma unroll
    for (int q = 0; q < 2; ++q) {
      int e = p * 2 + q;
      int k = ks * 32 + 4 * g + (e & 3) + 16 * (e >> 2);
      int col = ct * 16 + rr;
      h2v[q] = f2bf(W[k * NHID + col]);
    }
    hw[p] = (uint)h2v[0] | ((uint)h2v[1] << 16);
  }
  size_t o = ((size_t)fb * 64 + l) * 8;
  uint4 hv; hv.x = hw[0]; hv.y = hw[1]; hv.z = hw[2]; hv.w = hw[3];
  *(uint4*)&Bh[o] = hv;
}

// ---------------- MFMA bf16 GEMM1 + fused scores + bf16 output ----------------
// (unchanged from R9: gload_lds staging, swizzled source, cvt_pk at read)

__global__ __launch_bounds__(256, 4) void gemm1_mfma(const float* __restrict__ A,
    const ushort* __restrict__ Bh,
    const float* __restrict__ asrc, const float* __restrict__ adst,
    ushort* __restrict__ h1b, float* __restrict__ ssrc1, float* __restrict__ sdst1,
    int M) {
  __shared__ float A_s[2][64 * 64];
  const int tid = threadIdx.x;
  const int lane = tid & 63;
  const int wc = tid >> 6;
  const int g = lane >> 4, rr = lane & 15;
  const int row0 = blockIdx.x * 64;

  f32x4 acc[4][4] = {};

  auto stage = [&](int ki, int buf) {
    #pragma unroll
    for (int j = 0; j < 4; ++j) {
      int grp = wc * 4 + j;
      int s = grp * 64 + lane;
      int r = s >> 4;
      int us = s & 15;
      int ud = us ^ (r & 7);
      int gr = row0 + r;
      if (gr >= M) gr = M - 1;
      const float* src = &A[(size_t)gr * NFEAT + ki * 64 + ud * 4];
      float* dst = &A_s[buf][grp * 256];
      __builtin_amdgcn_global_load_lds(
          (const __attribute__((address_space(1))) float*)src,
          (__attribute__((address_space(3))) float*)dst, 16, 0, 0);
    }
  };

  stage(0, 0);
  __syncthreads();

  for (int ki = 0; ki < 8; ++ki) {
    const int cur = ki & 1;
    if (ki < 7) stage(ki + 1, cur ^ 1);

    #pragma unroll
    for (int kk = 0; kk < 2; ++kk) {
      const int ks = ki * 2 + kk;
      bf16x8 bhf[4];
      #pragma unroll
      for (int ni = 0; ni < 4; ++ni) {
        int ct = wc * 4 + ni;
        size_t bidx = ((size_t)(ct * 16 + ks) * 64 + lane) * 8;
        bhf[ni] = *(const bf16x8*)&Bh[bidx];
      }
      #pragma unroll
      for (int mi = 0; mi < 4; ++mi) {
        int row = mi * 16 + rr;
        int u0 = (8 * kk + g) ^ (row & 7);
        int u1 = (8 * kk + 4 + g) ^ (row & 7);
        f32x4 lo = *(const f32x4*)&A_s[cur][row * 64 + u0 * 4];
        f32x4 hi = *(const f32x4*)&A_s[cur][row * 64 + u1 * 4];
        uint w0 = cvtpk(lo[0], lo[1]);
        uint w1 = cvtpk(lo[2], lo[3]);
        uint w2 = cvtpk(hi[0], hi[1]);
        uint w3 = cvtpk(hi[2], hi[3]);
        union { uint u[4]; bf16x8 v; } af;
        af.u[0] = w0; af.u[1] = w1; af.u[2] = w2; af.u[3] = w3;
        #pragma unroll
        for (int ni = 0; ni < 4; ++ni) {
          acc[mi][ni] = __builtin_amdgcn_mfma_f32_16x16x32_bf16(af.v, bhf[ni], acc[mi][ni], 0, 0, 0);
        }
      }
    }
    __syncthreads();
  }

  float a_s[4], a_d[4];
  #pragma unroll
  for (int ni = 0; ni < 4; ++ni) {
    a_s[ni] = asrc[wc * 64 + ni * 16 + rr];
    a_d[ni] = adst[wc * 64 + ni * 16 + rr];
  }

  #pragma unroll
  for (int mi = 0; mi < 4; ++mi) {
    #pragma unroll
    for (int j = 0; j < 4; ++j) {
      int r = row0 + mi * 16 + g * 4 + j;
      bool ok = r < M;
      float ps = 0.f, pd = 0.f;
      #pragma unroll
      for (int ni = 0; ni < 4; ++ni) {
        float v = acc[mi][ni][j];
        ps += v * a_s[ni];
        pd += v * a_d[ni];
        if (ok) h1b[(size_t)r * NHID + wc * 64 + ni * 16 + rr] = f2bf(v);
      }
      #pragma unroll
      for (int m = 1; m < 16; m <<= 1) {
        ps += __shfl_xor(ps, m, 64);
        pd += __shfl_xor(pd, m, 64);
      }
      if (ok && rr == 0) {
        ssrc1[r * HEADS + wc] = ps;
        sdst1[r * HEADS + wc] = pd;
      }
    }
  }
}

// ---------------- layer-2 GEMM fused (A = bf16 hrelu) ----------------

__global__ __launch_bounds__(256) void gemm2_fused(const ushort* __restrict__ A,
    const float* __restrict__ B, const float* __restrict__ asrc,
    const float* __restrict__ adst, ushort* __restrict__ h2b,
    float* __restrict__ ssrc2, float* __restrict__ sdst2, int M) {
  __shared__ float As[16][64 + 1];
  __shared__ float Bs[16][68];
  const int tid = threadIdx.x;
  const int tx = tid & 15, ty = tid >> 4;
  const int row0 = blockIdx.x * 64;
  float acc[4][4] = {};

  const int la_r = tid >> 2;
  const int la_k = (tid & 3) * 4;
  const int lb_r = tid >> 4;
  const int lb_c = (tid & 15) * 4;

  for (int k0 = 0; k0 < NHID; k0 += 16) {
    float a0 = 0.f, a1 = 0.f, a2 = 0.f, a3 = 0.f;
    int ar = row0 + la_r;
    if (ar < M) {
      ushort4 uv = *(const ushort4*)&A[(size_t)ar * NHID + k0 + la_k];
      a0 = bf2f(uv.x); a1 = bf2f(uv.y); a2 = bf2f(uv.z); a3 = bf2f(uv.w);
    }
    As[la_k + 0][la_r] = a0;
    As[la_k + 1][la_r] = a1;
    As[la_k + 2][la_r] = a2;
    As[la_k + 3][la_r] = a3;

    float4 bv = make_float4(0.f, 0.f, 0.f, 0.f);
    const float* Brow = &B[(size_t)(k0 + lb_r) * NCLASS];
    if (lb_c + 3 < NCLASS) bv = *(const float4*)&Brow[lb_c];
    *(float4*)&Bs[lb_r][lb_c] = bv;
    __syncthreads();

    #pragma unroll
    for (int k = 0; k < 16; ++k) {
      float x0 = As[k][ty * 4 + 0];
      float x1 = As[k][ty * 4 + 1];
      float x2 = As[k][ty * 4 + 2];
      float x3 = As[k][ty * 4 + 3];
      float4 b = *(const float4*)&Bs[k][tx * 4];
      acc[0][0] += x0 * b.x; acc[0][1] += x0 * b.y; acc[0][2] += x0 * b.z; acc[0][3] += x0 * b.w;
      acc[1][0] += x1 * b.x; acc[1][1] += x1 * b.y; acc[1][2] += x1 * b.z; acc[1][3] += x1 * b.w;
      acc[2][0] += x2 * b.x; acc[2][1] += x2 * b.y; acc[2][2] += x2 * b.z; acc[2][3] += x2 * b.w;
      acc[3][0] += x3 * b.x; acc[3][1] += x3 * b.y; acc[3][2] += x3 * b.z; acc[3][3] += x3 * b.w;
    }
    __syncthreads();
  }

  const int cbase = tx * 4;
  const bool cok = cbase + 3 < NCLASS;   // tx <= 9
  float4 av_s = make_float4(0.f, 0.f, 0.f, 0.f);
  float4 av_d = make_float4(0.f, 0.f, 0.f, 0.f);
  if (cok) {
    av_s = *(const float4*)&asrc[cbase];
    av_d = *(const float4*)&adst[cbase];
  }

  #pragma unroll
  for (int i = 0; i < 4; ++i) {
    int r = row0 + ty * 4 + i;
    bool ok = r < M;
    float ps = acc[i][0] * av_s.x + acc[i][1] * av_s.y + acc[i][2] * av_s.z + acc[i][3] * av_s.w;
    float pd = acc[i][0] * av_d.x + acc[i][1] * av_d.y + acc[i][2] * av_d.z + acc[i][3] * av_d.w;
    #pragma unroll
    for (int m = 1; m < 16; m <<= 1) {
      ps += __shfl_xor(ps, m, 64);
      pd += __shfl_xor(pd, m, 64);
    }
    if (ok && cok) {
      ushort4 o;
      o.x = f2bf(acc[i][0]); o.y = f2bf(acc[i][1]);
      o.z = f2bf(acc[i][2]); o.w = f2bf(acc[i][3]);
      *(ushort4*)&h2b[(size_t)r * NCLASS + cbase] = o;
    }
    if (ok && tx == 0) { ssrc2[r] = ps; sdst2[r] = pd; }
  }
}

// ---------------- fused softmax + aggregation ----------------
// Batched edge weights (R15 structure, kept): one wave per node.

__global__ __launch_bounds__(64) void agg1_kernel(const ushort* __restrict__ h1b,
    const float* __restrict__ s_src, const float* __restrict__ s_dst,
    const int* __restrict__ row_off, const int* __restrict__ edge_src,
    const float* __restrict__ b1, ushort* __restrict__ hrelu_b) {
  int v = blockIdx.x;
  int l = threadIdx.x;
  int head = l >> 4;
  int elane = l & 15;
  int c = l * 4;
  float sdv = s_dst[v * HEADS + head];

  float wself = __expf(lrelu(s_src[v * HEADS + head] + sdv));
  ushort4 hv = *(const ushort4*)&h1b[(size_t)v * NHID + c];
  float4 acc = make_float4(wself * bf2f(hv.x), wself * bf2f(hv.y),
                           wself * bf2f(hv.z), wself * bf2f(hv.w));
  float zp = (elane == 0) ? wself : 0.f;

  int i = row_off[v], end = row_off[v + 1];
  for (; i < end; i += 16) {
    int cnt = end - i;
    if (cnt > 16) cnt = 16;
    bool val = elane < cnt;
    int u = edge_src[val ? (i + elane) : i];
    float wl = 0.f;
    if (val) wl = __expf(lrelu(s_src[u * HEADS + head] + sdv));
    zp += wl;

    int e = 0;
    for (; e + 3 < cnt; e += 4) {
      int u0 = __shfl(u, e + 0);
      int u1 = __shfl(u, e + 1);
      int u2 = __shfl(u, e + 2);
      int u3 = __shfl(u, e + 3);
      float w0 = __shfl(wl, (l & 48) | (e + 0));
      float w1 = __shfl(wl, (l & 48) | (e + 1));
      float w2 = __shfl(wl, (l & 48) | (e + 2));
      float w3 = __shfl(wl, (l & 48) | (e + 3));
      ushort4 r0 = *(const ushort4*)&h1b[(size_t)u0 * NHID + c];
      ushort4 r1 = *(const ushort4*)&h1b[(size_t)u1 * NHID + c];
      ushort4 r2 = *(const ushort4*)&h1b[(size_t)u2 * NHID + c];
      ushort4 r3 = *(const ushort4*)&h1b[(size_t)u3 * NHID + c];
      acc.x += w0 * bf2f(r0.x) + w1 * bf2f(r1.x) + w2 * bf2f(r2.x) + w3 * bf2f(r3.x);
      acc.y += w0 * bf2f(r0.y) + w1 * bf2f(r1.y) + w2 * bf2f(r2.y) + w3 * bf2f(r3.y);
      acc.z += w0 * bf2f(r0.z) + w1 * bf2f(r1.z) + w2 * bf2f(r2.z) + w3 * bf2f(r3.z);
      acc.w += w0 * bf2f(r0.w) + w1 * bf2f(r1.w) + w2 * bf2f(r2.w) + w3 * bf2f(r3.w);
    }
    for (; e < cnt; ++e) {
      int ue = __shfl(u, e);
      float we = __shfl(wl, (l & 48) | e);
      ushort4 ru = *(const ushort4*)&h1b[(size_t)ue * NHID + c];
      acc.x += we * bf2f(ru.x);
      acc.y += we * bf2f(ru.y);
      acc.z += we * bf2f(ru.z);
      acc.w += we * bf2f(ru.w);
    }
  }
  #pragma unroll
  for (int m = 1; m < 16; m <<= 1) zp += __shfl_xor(zp, m, 64);

  float inv = 1.f / (zp + EPS_Z);
  float4 bb = *(const float4*)&b1[c];
  ushort4 o;
  o.x = f2bf(fmaxf(acc.x * inv + bb.x, 0.f));
  o.y = f2bf(fmaxf(acc.y * inv + bb.y, 0.f));
  o.z = f2bf(fmaxf(acc.z * inv + bb.z, 0.f));
  o.w = f2bf(fmaxf(acc.w * inv + bb.w, 0.f));
  *(ushort4*)&hrelu_b[(size_t)v * NHID + c] = o;
}

__global__ __launch_bounds__(64) void agg2_kernel(const ushort* __restrict__ h2b,
    const float* __restrict__ s_src, const float* __restrict__ s_dst,
    const int* __restrict__ row_off, const int* __restrict__ edge_src,
    const float* __restrict__ b2, float* __restrict__ out) {
  int v = blockIdx.x;
  int l = threadIdx.x;
  bool act = l < NCLASS;
  float sdv = s_dst[v];

  float wself = __expf(lrelu(s_src[v] + sdv));
  float acc = act ? wself * bf2f(h2b[(size_t)v * NCLASS + l]) : 0.f;
  float zp = (l == 0) ? wself : 0.f;

  int i = row_off[v], end = row_off[v + 1];
  for (; i < end; i += 64) {
    int cnt = end - i;
    if (cnt > 64) cnt = 64;
    bool val = l < cnt;
    int u = edge_src[val ? (i + l) : i];
    float wl = 0.f;
    if (val) wl = __expf(lrelu(s_src[u] + sdv));
    zp += wl;

    int e = 0;
    for (; e + 3 < cnt; e += 4) {
      int u0 = __shfl(u, e + 0);
      int u1 = __shfl(u, e + 1);
      int u2 = __shfl(u, e + 2);
      int u3 = __shfl(u, e + 3);
      float w0 = __shfl(wl, e + 0);
      float w1 = __shfl(wl, e + 1);
      float w2 = __shfl(wl, e + 2);
      float w3 = __shfl(wl, e + 3);
      ushort p0 = 0, p1 = 0, p2 = 0, p3 = 0;
      if (act) {
        p0 = h2b[(size_t)u0 * NCLASS + l];
        p1 = h2b[(size_t)u1 * NCLASS + l];
        p2 = h2b[(size_t)u2 * NCLASS + l];
        p3 = h2b[(size_t)u3 * NCLASS + l];
      }
      if (act) acc += w0 * bf2f(p0) + w1 * bf2f(p1) + w2 * bf2f(p2) + w3 * bf2f(p3);
    }
    for (; e < cnt; ++e) {
      int ue = __shfl(u, e);
      float we = __shfl(wl, e);
      if (act) acc += we * bf2f(h2b[(size_t)ue * NCLASS + l]);
    }
  }
  #pragma unroll
  for (int m = 1; m < 64; m <<= 1) zp += __shfl_xor(zp, m, 64);

  if (act) out[(size_t)v * NCLASS + l] = acc / (zp + EPS_Z) + b2[l];
}

// ---------------- launch ----------------

extern "C" void kernel_launch(void* const* d_in, const int* in_sizes, int n_in,
                              void* d_out, int out_size, void* d_ws, size_t ws_size,
                              hipStream_t stream) {
  const float* x   = (const float*)d_in[0];
  const int*   adj = (const int*)d_in[1];
  const float* W1  = (const float*)d_in[2];
  const float* as1 = (const float*)d_in[3];
  const float* ad1 = (const float*)d_in[4];
  const float* b1  = (const float*)d_in[5];
  const float* W2  = (const float*)d_in[6];
  const float* as2 = (const float*)d_in[7];
  const float* ad2 = (const float*)d_in[8];
  const float* b2  = (const float*)d_in[9];
  float* out = (float*)d_out;

  int N = in_sizes[0] / NFEAT;   // 50000
  int E = in_sizes[1] / 2;       // 800000

  char* ws = (char*)d_ws;
  size_t off = 0;
  auto alloc = [&](size_t bytes) -> void* {
    void* p = ws + off;
    off = (off + bytes + 255) & ~(size_t)255;
    return p;
  };
  ushort* h1b    = (ushort*)alloc((size_t)N * NHID * 2);
  ushort* hrelub = (ushort*)alloc((size_t)N * NHID * 2);
  ushort* h2b    = (ushort*)alloc((size_t)N * NCLASS * 2);
  float* ssrc1   = (float*)alloc((size_t)N * HEADS * 4);
  float* sdst1   = (float*)alloc((size_t)N * HEADS * 4);
  float* ssrc2   = (float*)alloc((size_t)N * 4);
  float* sdst2   = (float*)alloc((size_t)N * 4);
  int* counts    = (int*)alloc((size_t)N * 4);
  int* cursor    = (int*)alloc((size_t)N * 4);
  int* row_off   = (int*)alloc((size_t)(N + 1) * 4);
  int* edge_src  = (int*)alloc((size_t)E * 4);
  int* bsum      = (int*)alloc((size_t)1024 * 4);
  ushort* whp    = (ushort*)alloc((size_t)NFEAT * NHID * 2);
  (void)ws_size;

  const int* srcv = adj;
  const int* dstv = adj + E;

  // W1 -> frag-major bf16
  wprep_kernel<<<256, 64, 0, stream>>>(W1, whp);

  // fused CSR construction (cooperative: zero->count->scan->scatter)
  {
    void* args[] = {(void*)&srcv, (void*)&dstv, (void*)&N, (void*)&E,
                    (void*)&counts, (void*)&row_off, (void*)&cursor,
                    (void*)&edge_src, (void*)&bsum};
    hipLaunchCooperativeKernel((void*)csr_kernel, dim3(CSR_BLOCKS),
                               dim3(CSR_THREADS), args, 0, stream);
  }

  // layer 1
  gemm1_mfma<<<(N + 63) / 64, 256, 0, stream>>>(x, whp, as1, ad1, h1b, ssrc1, sdst1, N);
  agg1_kernel<<<N, 64, 0, stream>>>(h1b, ssrc1, sdst1, row_off, edge_src, b1, hrelub);

  // layer 2
  gemm2_fused<<<(N + 63) / 64, 256, 0, stream>>>(hrelub, W2, as2, ad2, h2b, ssrc2, sdst2, N);
  agg2_kernel<<<N, 64, 0, stream>>>(h2b, ssrc2, sdst2, row_off, edge_src, b2, out);
}

// Round 18
// 268.800 us; speedup vs baseline: 1.4882x; 1.4882x over previous
//
#include <hip/hip_runtime.h>
#include <hip/hip_bf16.h>
#include <math.h>

#define NFEAT 512
#define NHID 256
#define HEADS 4
#define HDIM 64
#define NCLASS 40
#define NEG_SLOPE 0.2f
#define EPS_Z 1e-16f

typedef short bf16x8 __attribute__((ext_vector_type(8)));
typedef float f32x4 __attribute__((ext_vector_type(4)));

__device__ __forceinline__ float lrelu(float x) {
  return x > 0.f ? x : NEG_SLOPE * x;
}

__device__ __forceinline__ ushort f2bf(float f) {
  union { float f; uint u; } c; c.f = f;
  uint u = c.u;
  uint r = u + 0x7FFFu + ((u >> 16) & 1u);
  return (ushort)(r >> 16);
}
__device__ __forceinline__ float bf2f(ushort h) {
  union { uint u; float f; } c; c.u = ((uint)h) << 16;
  return c.f;
}

// packed f32x2 -> bf16x2 (RTNE), gfx950
__device__ __forceinline__ uint cvtpk(float lo, float hi) {
  uint r;
  asm("v_cvt_pk_bf16_f32 %0, %1, %2" : "=v"(r) : "v"(lo), "v"(hi));
  return r;
}

// ---------------- CSR construction ----------------

__global__ void count_kernel(const int* __restrict__ dstv, int E, int* __restrict__ counts) {
  int i = blockIdx.x * blockDim.x + threadIdx.x;
  if (i < E) atomicAdd(&counts[dstv[i]], 1);
}

__global__ __launch_bounds__(1024) void scan_a(const int* __restrict__ counts,
    int* __restrict__ excl, int* __restrict__ bsum, int n) {
  __shared__ int tmp[1024];
  int t = threadIdx.x;
  int i = blockIdx.x * 1024 + t;
  int v = (i < n) ? counts[i] : 0;
  tmp[t] = v;
  __syncthreads();
  for (int off = 1; off < 1024; off <<= 1) {
    int u = (t >= off) ? tmp[t - off] : 0;
    __syncthreads();
    tmp[t] += u;
    __syncthreads();
  }
  if (i < n) excl[i] = tmp[t] - v;
  if (t == 1023) bsum[blockIdx.x] = tmp[t];
}

__global__ __launch_bounds__(1024) void scan_b(int* __restrict__ bsum, int nb) {
  __shared__ int tmp[1024];
  int t = threadIdx.x;
  tmp[t] = (t < nb) ? bsum[t] : 0;
  __syncthreads();
  for (int off = 1; off < 1024; off <<= 1) {
    int u = (t >= off) ? tmp[t - off] : 0;
    __syncthreads();
    tmp[t] += u;
    __syncthreads();
  }
  if (t < nb) bsum[t] = tmp[t];
}

__global__ void scan_c(const int* __restrict__ excl, const int* __restrict__ bsum_incl,
    int* __restrict__ row_off, int* __restrict__ cursor, int n, int E) {
  int i = blockIdx.x * blockDim.x + threadIdx.x;
  if (i < n) {
    int b = i >> 10;
    int off = (b > 0) ? bsum_incl[b - 1] : 0;
    int v = excl[i] + off;
    row_off[i] = v;
    cursor[i] = v;
  }
  if (i == 0) row_off[n] = E;
}

__global__ void scatter_kernel(const int* __restrict__ srcv, const int* __restrict__ dstv,
                               int E, int* __restrict__ cursor, int* __restrict__ edge_src) {
  int i = blockIdx.x * blockDim.x + threadIdx.x;
  if (i < E) {
    int pos = atomicAdd(&cursor[dstv[i]], 1);
    edge_src[pos] = srcv[i];
  }
}

// ---------------- W1 prep: f32 [512][256] -> frag-major bf16 ----------------

__global__ __launch_bounds__(64) void wprep_kernel(const float* __restrict__ W,
    ushort* __restrict__ Bh) {
  int fb = blockIdx.x;          // ct*16 + ks, 256 blocks
  int ct = fb >> 4, ks = fb & 15;
  int l = threadIdx.x;
  int g = l >> 4, rr = l & 15;
  uint hw[4];
  #pragma unroll
  for (int p = 0; p < 4; ++p) {
    ushort h2v[2];
    #pragma unroll
    for (int q = 0; q < 2; ++q) {
      int e = p * 2 + q;
      int k = ks * 32 + 4 * g + (e & 3) + 16 * (e >> 2);
      int col = ct * 16 + rr;
      h2v[q] = f2bf(W[k * NHID + col]);
    }
    hw[p] = (uint)h2v[0] | ((uint)h2v[1] << 16);
  }
  size_t o = ((size_t)fb * 64 + l) * 8;
  uint4 hv; hv.x = hw[0]; hv.y = hw[1]; hv.z = hw[2]; hv.w = hw[3];
  *(uint4*)&Bh[o] = hv;
}

// ---------------- MFMA bf16 GEMM1 + fused scores + bf16 output ----------------
// (R9 structure: gload_lds staging, swizzled source, cvt_pk at read)

__global__ __launch_bounds__(256, 4) void gemm1_mfma(const float* __restrict__ A,
    const ushort* __restrict__ Bh,
    const float* __restrict__ asrc, const float* __restrict__ adst,
    ushort* __restrict__ h1b, float* __restrict__ ssrc1, float* __restrict__ sdst1,
    int M) {
  __shared__ float A_s[2][64 * 64];
  const int tid = threadIdx.x;
  const int lane = tid & 63;
  const int wc = tid >> 6;
  const int g = lane >> 4, rr = lane & 15;
  const int row0 = blockIdx.x * 64;

  f32x4 acc[4][4] = {};

  auto stage = [&](int ki, int buf) {
    #pragma unroll
    for (int j = 0; j < 4; ++j) {
      int grp = wc * 4 + j;
      int s = grp * 64 + lane;
      int r = s >> 4;
      int us = s & 15;
      int ud = us ^ (r & 7);
      int gr = row0 + r;
      if (gr >= M) gr = M - 1;
      const float* src = &A[(size_t)gr * NFEAT + ki * 64 + ud * 4];
      float* dst = &A_s[buf][grp * 256];
      __builtin_amdgcn_global_load_lds(
          (const __attribute__((address_space(1))) float*)src,
          (__attribute__((address_space(3))) float*)dst, 16, 0, 0);
    }
  };

  stage(0, 0);
  __syncthreads();

  for (int ki = 0; ki < 8; ++ki) {
    const int cur = ki & 1;
    if (ki < 7) stage(ki + 1, cur ^ 1);

    #pragma unroll
    for (int kk = 0; kk < 2; ++kk) {
      const int ks = ki * 2 + kk;
      bf16x8 bhf[4];
      #pragma unroll
      for (int ni = 0; ni < 4; ++ni) {
        int ct = wc * 4 + ni;
        size_t bidx = ((size_t)(ct * 16 + ks) * 64 + lane) * 8;
        bhf[ni] = *(const bf16x8*)&Bh[bidx];
      }
      #pragma unroll
      for (int mi = 0; mi < 4; ++mi) {
        int row = mi * 16 + rr;
        int u0 = (8 * kk + g) ^ (row & 7);
        int u1 = (8 * kk + 4 + g) ^ (row & 7);
        f32x4 lo = *(const f32x4*)&A_s[cur][row * 64 + u0 * 4];
        f32x4 hi = *(const f32x4*)&A_s[cur][row * 64 + u1 * 4];
        uint w0 = cvtpk(lo[0], lo[1]);
        uint w1 = cvtpk(lo[2], lo[3]);
        uint w2 = cvtpk(hi[0], hi[1]);
        uint w3 = cvtpk(hi[2], hi[3]);
        union { uint u[4]; bf16x8 v; } af;
        af.u[0] = w0; af.u[1] = w1; af.u[2] = w2; af.u[3] = w3;
        #pragma unroll
        for (int ni = 0; ni < 4; ++ni) {
          acc[mi][ni] = __builtin_amdgcn_mfma_f32_16x16x32_bf16(af.v, bhf[ni], acc[mi][ni], 0, 0, 0);
        }
      }
    }
    __syncthreads();
  }

  float a_s[4], a_d[4];
  #pragma unroll
  for (int ni = 0; ni < 4; ++ni) {
    a_s[ni] = asrc[wc * 64 + ni * 16 + rr];
    a_d[ni] = adst[wc * 64 + ni * 16 + rr];
  }

  #pragma unroll
  for (int mi = 0; mi < 4; ++mi) {
    #pragma unroll
    for (int j = 0; j < 4; ++j) {
      int r = row0 + mi * 16 + g * 4 + j;
      bool ok = r < M;
      float ps = 0.f, pd = 0.f;
      #pragma unroll
      for (int ni = 0; ni < 4; ++ni) {
        float v = acc[mi][ni][j];
        ps += v * a_s[ni];
        pd += v * a_d[ni];
        if (ok) h1b[(size_t)r * NHID + wc * 64 + ni * 16 + rr] = f2bf(v);
      }
      #pragma unroll
      for (int m = 1; m < 16; m <<= 1) {
        ps += __shfl_xor(ps, m, 64);
        pd += __shfl_xor(pd, m, 64);
      }
      if (ok && rr == 0) {
        ssrc1[r * HEADS + wc] = ps;
        sdst1[r * HEADS + wc] = pd;
      }
    }
  }
}

// ---------------- layer-2 GEMM fused (A = bf16 hrelu) ----------------

__global__ __launch_bounds__(256) void gemm2_fused(const ushort* __restrict__ A,
    const float* __restrict__ B, const float* __restrict__ asrc,
    const float* __restrict__ adst, ushort* __restrict__ h2b,
    float* __restrict__ ssrc2, float* __restrict__ sdst2, int M) {
  __shared__ float As[16][64 + 1];
  __shared__ float Bs[16][68];
  const int tid = threadIdx.x;
  const int tx = tid & 15, ty = tid >> 4;
  const int row0 = blockIdx.x * 64;
  float acc[4][4] = {};

  const int la_r = tid >> 2;
  const int la_k = (tid & 3) * 4;
  const int lb_r = tid >> 4;
  const int lb_c = (tid & 15) * 4;

  for (int k0 = 0; k0 < NHID; k0 += 16) {
    float a0 = 0.f, a1 = 0.f, a2 = 0.f, a3 = 0.f;
    int ar = row0 + la_r;
    if (ar < M) {
      ushort4 uv = *(const ushort4*)&A[(size_t)ar * NHID + k0 + la_k];
      a0 = bf2f(uv.x); a1 = bf2f(uv.y); a2 = bf2f(uv.z); a3 = bf2f(uv.w);
    }
    As[la_k + 0][la_r] = a0;
    As[la_k + 1][la_r] = a1;
    As[la_k + 2][la_r] = a2;
    As[la_k + 3][la_r] = a3;

    float4 bv = make_float4(0.f, 0.f, 0.f, 0.f);
    const float* Brow = &B[(size_t)(k0 + lb_r) * NCLASS];
    if (lb_c + 3 < NCLASS) bv = *(const float4*)&Brow[lb_c];
    *(float4*)&Bs[lb_r][lb_c] = bv;
    __syncthreads();

    #pragma unroll
    for (int k = 0; k < 16; ++k) {
      float x0 = As[k][ty * 4 + 0];
      float x1 = As[k][ty * 4 + 1];
      float x2 = As[k][ty * 4 + 2];
      float x3 = As[k][ty * 4 + 3];
      float4 b = *(const float4*)&Bs[k][tx * 4];
      acc[0][0] += x0 * b.x; acc[0][1] += x0 * b.y; acc[0][2] += x0 * b.z; acc[0][3] += x0 * b.w;
      acc[1][0] += x1 * b.x; acc[1][1] += x1 * b.y; acc[1][2] += x1 * b.z; acc[1][3] += x1 * b.w;
      acc[2][0] += x2 * b.x; acc[2][1] += x2 * b.y; acc[2][2] += x2 * b.z; acc[2][3] += x2 * b.w;
      acc[3][0] += x3 * b.x; acc[3][1] += x3 * b.y; acc[3][2] += x3 * b.z; acc[3][3] += x3 * b.w;
    }
    __syncthreads();
  }

  const int cbase = tx * 4;
  const bool cok = cbase + 3 < NCLASS;   // tx <= 9
  float4 av_s = make_float4(0.f, 0.f, 0.f, 0.f);
  float4 av_d = make_float4(0.f, 0.f, 0.f, 0.f);
  if (cok) {
    av_s = *(const float4*)&asrc[cbase];
    av_d = *(const float4*)&adst[cbase];
  }

  #pragma unroll
  for (int i = 0; i < 4; ++i) {
    int r = row0 + ty * 4 + i;
    bool ok = r < M;
    float ps = acc[i][0] * av_s.x + acc[i][1] * av_s.y + acc[i][2] * av_s.z + acc[i][3] * av_s.w;
    float pd = acc[i][0] * av_d.x + acc[i][1] * av_d.y + acc[i][2] * av_d.z + acc[i][3] * av_d.w;
    #pragma unroll
    for (int m = 1; m < 16; m <<= 1) {
      ps += __shfl_xor(ps, m, 64);
      pd += __shfl_xor(pd, m, 64);
    }
    if (ok && cok) {
      ushort4 o;
      o.x = f2bf(acc[i][0]); o.y = f2bf(acc[i][1]);
      o.z = f2bf(acc[i][2]); o.w = f2bf(acc[i][3]);
      *(ushort4*)&h2b[(size_t)r * NCLASS + cbase] = o;
    }
    if (ok && tx == 0) { ssrc2[r] = ps; sdst2[r] = pd; }
  }
}

// ---------------- fused softmax + aggregation ----------------
// Batched edge weights: one wave per node; per 16-edge block, lane (e,head)
// computes ONE score-gather + ONE exp for its pair; payload gather reads the
// weight via shfl. z accumulates per lane, one 16-group reduce at the end.

__global__ __launch_bounds__(64) void agg1_kernel(const ushort* __restrict__ h1b,
    const float* __restrict__ s_src, const float* __restrict__ s_dst,
    const int* __restrict__ row_off, const int* __restrict__ edge_src,
    const float* __restrict__ b1, ushort* __restrict__ hrelu_b) {
  int v = blockIdx.x;
  int l = threadIdx.x;
  int head = l >> 4;
  int elane = l & 15;
  int c = l * 4;
  float sdv = s_dst[v * HEADS + head];

  // self-loop
  float wself = __expf(lrelu(s_src[v * HEADS + head] + sdv));
  ushort4 hv = *(const ushort4*)&h1b[(size_t)v * NHID + c];
  float4 acc = make_float4(wself * bf2f(hv.x), wself * bf2f(hv.y),
                           wself * bf2f(hv.z), wself * bf2f(hv.w));
  float zp = (elane == 0) ? wself : 0.f;

  int i = row_off[v], end = row_off[v + 1];
  for (; i < end; i += 16) {
    int cnt = end - i;
    if (cnt > 16) cnt = 16;
    bool val = elane < cnt;
    int u = edge_src[val ? (i + elane) : i];
    float wl = 0.f;
    if (val) wl = __expf(lrelu(s_src[u * HEADS + head] + sdv));
    zp += wl;

    int e = 0;
    for (; e + 3 < cnt; e += 4) {
      int u0 = __shfl(u, e + 0);
      int u1 = __shfl(u, e + 1);
      int u2 = __shfl(u, e + 2);
      int u3 = __shfl(u, e + 3);
      float w0 = __shfl(wl, (l & 48) | (e + 0));
      float w1 = __shfl(wl, (l & 48) | (e + 1));
      float w2 = __shfl(wl, (l & 48) | (e + 2));
      float w3 = __shfl(wl, (l & 48) | (e + 3));
      ushort4 r0 = *(const ushort4*)&h1b[(size_t)u0 * NHID + c];
      ushort4 r1 = *(const ushort4*)&h1b[(size_t)u1 * NHID + c];
      ushort4 r2 = *(const ushort4*)&h1b[(size_t)u2 * NHID + c];
      ushort4 r3 = *(const ushort4*)&h1b[(size_t)u3 * NHID + c];
      acc.x += w0 * bf2f(r0.x) + w1 * bf2f(r1.x) + w2 * bf2f(r2.x) + w3 * bf2f(r3.x);
      acc.y += w0 * bf2f(r0.y) + w1 * bf2f(r1.y) + w2 * bf2f(r2.y) + w3 * bf2f(r3.y);
      acc.z += w0 * bf2f(r0.z) + w1 * bf2f(r1.z) + w2 * bf2f(r2.z) + w3 * bf2f(r3.z);
      acc.w += w0 * bf2f(r0.w) + w1 * bf2f(r1.w) + w2 * bf2f(r2.w) + w3 * bf2f(r3.w);
    }
    for (; e < cnt; ++e) {
      int ue = __shfl(u, e);
      float we = __shfl(wl, (l & 48) | e);
      ushort4 ru = *(const ushort4*)&h1b[(size_t)ue * NHID + c];
      acc.x += we * bf2f(ru.x);
      acc.y += we * bf2f(ru.y);
      acc.z += we * bf2f(ru.z);
      acc.w += we * bf2f(ru.w);
    }
  }
  #pragma unroll
  for (int m = 1; m < 16; m <<= 1) zp += __shfl_xor(zp, m, 64);

  float inv = 1.f / (zp + EPS_Z);
  float4 bb = *(const float4*)&b1[c];
  ushort4 o;
  o.x = f2bf(fmaxf(acc.x * inv + bb.x, 0.f));
  o.y = f2bf(fmaxf(acc.y * inv + bb.y, 0.f));
  o.z = f2bf(fmaxf(acc.z * inv + bb.z, 0.f));
  o.w = f2bf(fmaxf(acc.w * inv + bb.w, 0.f));
  *(ushort4*)&hrelu_b[(size_t)v * NHID + c] = o;
}

// agg2: EB=64 (single head) — all 64 lanes compute one edge's exp in parallel.
__global__ __launch_bounds__(64) void agg2_kernel(const ushort* __restrict__ h2b,
    const float* __restrict__ s_src, const float* __restrict__ s_dst,
    const int* __restrict__ row_off, const int* __restrict__ edge_src,
    const float* __restrict__ b2, float* __restrict__ out) {
  int v = blockIdx.x;
  int l = threadIdx.x;
  bool act = l < NCLASS;
  float sdv = s_dst[v];

  float wself = __expf(lrelu(s_src[v] + sdv));
  float acc = act ? wself * bf2f(h2b[(size_t)v * NCLASS + l]) : 0.f;
  float zp = (l == 0) ? wself : 0.f;

  int i = row_off[v], end = row_off[v + 1];
  for (; i < end; i += 64) {
    int cnt = end - i;
    if (cnt > 64) cnt = 64;
    bool val = l < cnt;
    int u = edge_src[val ? (i + l) : i];
    float wl = 0.f;
    if (val) wl = __expf(lrelu(s_src[u] + sdv));
    zp += wl;

    int e = 0;
    for (; e + 3 < cnt; e += 4) {
      int u0 = __shfl(u, e + 0);
      int u1 = __shfl(u, e + 1);
      int u2 = __shfl(u, e + 2);
      int u3 = __shfl(u, e + 3);
      float w0 = __shfl(wl, e + 0);
      float w1 = __shfl(wl, e + 1);
      float w2 = __shfl(wl, e + 2);
      float w3 = __shfl(wl, e + 3);
      ushort p0 = 0, p1 = 0, p2 = 0, p3 = 0;
      if (act) {
        p0 = h2b[(size_t)u0 * NCLASS + l];
        p1 = h2b[(size_t)u1 * NCLASS + l];
        p2 = h2b[(size_t)u2 * NCLASS + l];
        p3 = h2b[(size_t)u3 * NCLASS + l];
      }
      if (act) acc += w0 * bf2f(p0) + w1 * bf2f(p1) + w2 * bf2f(p2) + w3 * bf2f(p3);
    }
    for (; e < cnt; ++e) {
      int ue = __shfl(u, e);
      float we = __shfl(wl, e);
      if (act) acc += we * bf2f(h2b[(size_t)ue * NCLASS + l]);
    }
  }
  #pragma unroll
  for (int m = 1; m < 64; m <<= 1) zp += __shfl_xor(zp, m, 64);

  if (act) out[(size_t)v * NCLASS + l] = acc / (zp + EPS_Z) + b2[l];
}

// ---------------- launch ----------------

extern "C" void kernel_launch(void* const* d_in, const int* in_sizes, int n_in,
                              void* d_out, int out_size, void* d_ws, size_t ws_size,
                              hipStream_t stream) {
  const float* x   = (const float*)d_in[0];
  const int*   adj = (const int*)d_in[1];
  const float* W1  = (const float*)d_in[2];
  const float* as1 = (const float*)d_in[3];
  const float* ad1 = (const float*)d_in[4];
  const float* b1  = (const float*)d_in[5];
  const float* W2  = (const float*)d_in[6];
  const float* as2 = (const float*)d_in[7];
  const float* ad2 = (const float*)d_in[8];
  const float* b2  = (const float*)d_in[9];
  float* out = (float*)d_out;

  const int N = in_sizes[0] / NFEAT;   // 50000
  const int E = in_sizes[1] / 2;       // 800000

  char* ws = (char*)d_ws;
  size_t off = 0;
  auto alloc = [&](size_t bytes) -> void* {
    void* p = ws + off;
    off = (off + bytes + 255) & ~(size_t)255;
    return p;
  };
  ushort* h1b    = (ushort*)alloc((size_t)N * NHID * 2);
  ushort* hrelub = (ushort*)alloc((size_t)N * NHID * 2);
  ushort* h2b    = (ushort*)alloc((size_t)N * NCLASS * 2);
  float* ssrc1   = (float*)alloc((size_t)N * HEADS * 4);
  float* sdst1   = (float*)alloc((size_t)N * HEADS * 4);
  float* ssrc2   = (float*)alloc((size_t)N * 4);
  float* sdst2   = (float*)alloc((size_t)N * 4);
  int* counts    = (int*)alloc((size_t)N * 4);
  int* cursor    = (int*)alloc((size_t)N * 4);
  int* row_off   = (int*)alloc((size_t)(N + 1) * 4);
  int* edge_src  = (int*)alloc((size_t)E * 4);
  int* excl      = (int*)alloc((size_t)N * 4);
  int* bsum      = (int*)alloc((size_t)1024 * 4);
  ushort* whp    = (ushort*)alloc((size_t)NFEAT * NHID * 2);
  (void)ws_size;

  const int* srcv = adj;
  const int* dstv = adj + E;
  const int nb = (N + 1023) / 1024;

  // W1 -> frag-major bf16
  wprep_kernel<<<256, 64, 0, stream>>>(W1, whp);

  // CSR by dst (parallel 3-phase scan)
  hipMemsetAsync(counts, 0, (size_t)N * 4, stream);
  count_kernel<<<(E + 255) / 256, 256, 0, stream>>>(dstv, E, counts);
  scan_a<<<nb, 1024, 0, stream>>>(counts, excl, bsum, N);
  scan_b<<<1, 1024, 0, stream>>>(bsum, nb);
  scan_c<<<(N + 255) / 256, 256, 0, stream>>>(excl, bsum, row_off, cursor, N, E);
  scatter_kernel<<<(E + 255) / 256, 256, 0, stream>>>(srcv, dstv, E, cursor, edge_src);

  // layer 1
  gemm1_mfma<<<(N + 63) / 64, 256, 0, stream>>>(x, whp, as1, ad1, h1b, ssrc1, sdst1, N);
  agg1_kernel<<<N, 64, 0, stream>>>(h1b, ssrc1, sdst1, row_off, edge_src, b1, hrelub);

  // layer 2
  gemm2_fused<<<(N + 63) / 64, 256, 0, stream>>>(hrelub, W2, as2, ad2, h2b, ssrc2, sdst2, N);
  agg2_kernel<<<N, 64, 0, stream>>>(h2b, ssrc2, sdst2, row_off, edge_src, b2, out);
}

// Round 21
// 265.756 us; speedup vs baseline: 1.5052x; 1.0115x over previous
//
#include <hip/hip_runtime.h>
#include <hip/hip_bf16.h>
#include <math.h>

#define NFEAT 512
#define NHID 256
#define HEADS 4
#define HDIM 64
#define NCLASS 40
#define NEG_SLOPE 0.2f
#define EPS_Z 1e-16f

typedef short bf16x8 __attribute__((ext_vector_type(8)));
typedef float f32x4 __attribute__((ext_vector_type(4)));

__device__ __forceinline__ float lrelu(float x) {
  return x > 0.f ? x : NEG_SLOPE * x;
}

__device__ __forceinline__ ushort f2bf(float f) {
  union { float f; uint u; } c; c.f = f;
  uint u = c.u;
  uint r = u + 0x7FFFu + ((u >> 16) & 1u);
  return (ushort)(r >> 16);
}
__device__ __forceinline__ float bf2f(ushort h) {
  union { uint u; float f; } c; c.u = ((uint)h) << 16;
  return c.f;
}

// packed f32x2 -> bf16x2 (RTNE), gfx950
__device__ __forceinline__ uint cvtpk(float lo, float hi) {
  uint r;
  asm("v_cvt_pk_bf16_f32 %0, %1, %2" : "=v"(r) : "v"(lo), "v"(hi));
  return r;
}

// ---------------- CSR construction ----------------

__global__ void count_kernel(const int* __restrict__ dstv, int E, int* __restrict__ counts) {
  int i = blockIdx.x * blockDim.x + threadIdx.x;
  if (i < E) atomicAdd(&counts[dstv[i]], 1);
}

__global__ __launch_bounds__(1024) void scan_a(const int* __restrict__ counts,
    int* __restrict__ excl, int* __restrict__ bsum, int n) {
  __shared__ int tmp[1024];
  int t = threadIdx.x;
  int i = blockIdx.x * 1024 + t;
  int v = (i < n) ? counts[i] : 0;
  tmp[t] = v;
  __syncthreads();
  for (int off = 1; off < 1024; off <<= 1) {
    int u = (t >= off) ? tmp[t - off] : 0;
    __syncthreads();
    tmp[t] += u;
    __syncthreads();
  }
  if (i < n) excl[i] = tmp[t] - v;
  if (t == 1023) bsum[blockIdx.x] = tmp[t];
}

__global__ __launch_bounds__(1024) void scan_b(int* __restrict__ bsum, int nb) {
  __shared__ int tmp[1024];
  int t = threadIdx.x;
  tmp[t] = (t < nb) ? bsum[t] : 0;
  __syncthreads();
  for (int off = 1; off < 1024; off <<= 1) {
    int u = (t >= off) ? tmp[t - off] : 0;
    __syncthreads();
    tmp[t] += u;
    __syncthreads();
  }
  if (t < nb) bsum[t] = tmp[t];
}

__global__ void scan_c(const int* __restrict__ excl, const int* __restrict__ bsum_incl,
    int* __restrict__ row_off, int* __restrict__ cursor, int n, int E) {
  int i = blockIdx.x * blockDim.x + threadIdx.x;
  if (i < n) {
    int b = i >> 10;
    int off = (b > 0) ? bsum_incl[b - 1] : 0;
    int v = excl[i] + off;
    row_off[i] = v;
    cursor[i] = v;
  }
  if (i == 0) row_off[n] = E;
}

__global__ void scatter_kernel(const int* __restrict__ srcv, const int* __restrict__ dstv,
                               int E, int* __restrict__ cursor, int* __restrict__ edge_src) {
  int i = blockIdx.x * blockDim.x + threadIdx.x;
  if (i < E) {
    int pos = atomicAdd(&cursor[dstv[i]], 1);
    edge_src[pos] = srcv[i];
  }
}

// ---------------- W1 prep: f32 [512][256] -> frag-major bf16 ----------------

__global__ __launch_bounds__(64) void wprep_kernel(const float* __restrict__ W,
    ushort* __restrict__ Bh) {
  int fb = blockIdx.x;          // ct*16 + ks, 256 blocks
  int ct = fb >> 4, ks = fb & 15;
  int l = threadIdx.x;
  int g = l >> 4, rr = l & 15;
  uint hw[4];
  #pragma unroll
  for (int p = 0; p < 4; ++p) {
    ushort h2v[2];
    #pragma unroll
    for (int q = 0; q < 2; ++q) {
      int e = p * 2 + q;
      int k = ks * 32 + 4 * g + (e & 3) + 16 * (e >> 2);
      int col = ct * 16 + rr;
      h2v[q] = f2bf(W[k * NHID + col]);
    }
    hw[p] = (uint)h2v[0] | ((uint)h2v[1] << 16);
  }
  size_t o = ((size_t)fb * 64 + l) * 8;
  uint4 hv; hv.x = hw[0]; hv.y = hw[1]; hv.z = hw[2]; hv.w = hw[3];
  *(uint4*)&Bh[o] = hv;
}

// ---------------- MFMA bf16 GEMM1 + fused scores + bf16 output ----------------
// (R9 structure: gload_lds staging, swizzled source, cvt_pk at read)

__global__ __launch_bounds__(256, 4) void gemm1_mfma(const float* __restrict__ A,
    const ushort* __restrict__ Bh,
    const float* __restrict__ asrc, const float* __restrict__ adst,
    ushort* __restrict__ h1b, float* __restrict__ ssrc1, float* __restrict__ sdst1,
    int M) {
  __shared__ float A_s[2][64 * 64];
  const int tid = threadIdx.x;
  const int lane = tid & 63;
  const int wc = tid >> 6;
  const int g = lane >> 4, rr = lane & 15;
  const int row0 = blockIdx.x * 64;

  f32x4 acc[4][4] = {};

  auto stage = [&](int ki, int buf) {
    #pragma unroll
    for (int j = 0; j < 4; ++j) {
      int grp = wc * 4 + j;
      int s = grp * 64 + lane;
      int r = s >> 4;
      int us = s & 15;
      int ud = us ^ (r & 7);
      int gr = row0 + r;
      if (gr >= M) gr = M - 1;
      const float* src = &A[(size_t)gr * NFEAT + ki * 64 + ud * 4];
      float* dst = &A_s[buf][grp * 256];
      __builtin_amdgcn_global_load_lds(
          (const __attribute__((address_space(1))) float*)src,
          (__attribute__((address_space(3))) float*)dst, 16, 0, 0);
    }
  };

  stage(0, 0);
  __syncthreads();

  for (int ki = 0; ki < 8; ++ki) {
    const int cur = ki & 1;
    if (ki < 7) stage(ki + 1, cur ^ 1);

    #pragma unroll
    for (int kk = 0; kk < 2; ++kk) {
      const int ks = ki * 2 + kk;
      bf16x8 bhf[4];
      #pragma unroll
      for (int ni = 0; ni < 4; ++ni) {
        int ct = wc * 4 + ni;
        size_t bidx = ((size_t)(ct * 16 + ks) * 64 + lane) * 8;
        bhf[ni] = *(const bf16x8*)&Bh[bidx];
      }
      #pragma unroll
      for (int mi = 0; mi < 4; ++mi) {
        int row = mi * 16 + rr;
        int u0 = (8 * kk + g) ^ (row & 7);
        int u1 = (8 * kk + 4 + g) ^ (row & 7);
        f32x4 lo = *(const f32x4*)&A_s[cur][row * 64 + u0 * 4];
        f32x4 hi = *(const f32x4*)&A_s[cur][row * 64 + u1 * 4];
        uint w0 = cvtpk(lo[0], lo[1]);
        uint w1 = cvtpk(lo[2], lo[3]);
        uint w2 = cvtpk(hi[0], hi[1]);
        uint w3 = cvtpk(hi[2], hi[3]);
        union { uint u[4]; bf16x8 v; } af;
        af.u[0] = w0; af.u[1] = w1; af.u[2] = w2; af.u[3] = w3;
        #pragma unroll
        for (int ni = 0; ni < 4; ++ni) {
          acc[mi][ni] = __builtin_amdgcn_mfma_f32_16x16x32_bf16(af.v, bhf[ni], acc[mi][ni], 0, 0, 0);
        }
      }
    }
    __syncthreads();
  }

  float a_s[4], a_d[4];
  #pragma unroll
  for (int ni = 0; ni < 4; ++ni) {
    a_s[ni] = asrc[wc * 64 + ni * 16 + rr];
    a_d[ni] = adst[wc * 64 + ni * 16 + rr];
  }

  #pragma unroll
  for (int mi = 0; mi < 4; ++mi) {
    #pragma unroll
    for (int j = 0; j < 4; ++j) {
      int r = row0 + mi * 16 + g * 4 + j;
      bool ok = r < M;
      float ps = 0.f, pd = 0.f;
      #pragma unroll
      for (int ni = 0; ni < 4; ++ni) {
        float v = acc[mi][ni][j];
        ps += v * a_s[ni];
        pd += v * a_d[ni];
        if (ok) h1b[(size_t)r * NHID + wc * 64 + ni * 16 + rr] = f2bf(v);
      }
      #pragma unroll
      for (int m = 1; m < 16; m <<= 1) {
        ps += __shfl_xor(ps, m, 64);
        pd += __shfl_xor(pd, m, 64);
      }
      if (ok && rr == 0) {
        ssrc1[r * HEADS + wc] = ps;
        sdst1[r * HEADS + wc] = pd;
      }
    }
  }
}

// ---------------- layer-2 GEMM fused (A = bf16 hrelu) ----------------

__global__ __launch_bounds__(256) void gemm2_fused(const ushort* __restrict__ A,
    const float* __restrict__ B, const float* __restrict__ asrc,
    const float* __restrict__ adst, ushort* __restrict__ h2b,
    float* __restrict__ ssrc2, float* __restrict__ sdst2, int M) {
  __shared__ float As[16][64 + 1];
  __shared__ float Bs[16][68];
  const int tid = threadIdx.x;
  const int tx = tid & 15, ty = tid >> 4;
  const int row0 = blockIdx.x * 64;
  float acc[4][4] = {};

  const int la_r = tid >> 2;
  const int la_k = (tid & 3) * 4;
  const int lb_r = tid >> 4;
  const int lb_c = (tid & 15) * 4;

  for (int k0 = 0; k0 < NHID; k0 += 16) {
    float a0 = 0.f, a1 = 0.f, a2 = 0.f, a3 = 0.f;
    int ar = row0 + la_r;
    if (ar < M) {
      ushort4 uv = *(const ushort4*)&A[(size_t)ar * NHID + k0 + la_k];
      a0 = bf2f(uv.x); a1 = bf2f(uv.y); a2 = bf2f(uv.z); a3 = bf2f(uv.w);
    }
    As[la_k + 0][la_r] = a0;
    As[la_k + 1][la_r] = a1;
    As[la_k + 2][la_r] = a2;
    As[la_k + 3][la_r] = a3;

    float4 bv = make_float4(0.f, 0.f, 0.f, 0.f);
    const float* Brow = &B[(size_t)(k0 + lb_r) * NCLASS];
    if (lb_c + 3 < NCLASS) bv = *(const float4*)&Brow[lb_c];
    *(float4*)&Bs[lb_r][lb_c] = bv;
    __syncthreads();

    #pragma unroll
    for (int k = 0; k < 16; ++k) {
      float x0 = As[k][ty * 4 + 0];
      float x1 = As[k][ty * 4 + 1];
      float x2 = As[k][ty * 4 + 2];
      float x3 = As[k][ty * 4 + 3];
      float4 b = *(const float4*)&Bs[k][tx * 4];
      acc[0][0] += x0 * b.x; acc[0][1] += x0 * b.y; acc[0][2] += x0 * b.z; acc[0][3] += x0 * b.w;
      acc[1][0] += x1 * b.x; acc[1][1] += x1 * b.y; acc[1][2] += x1 * b.z; acc[1][3] += x1 * b.w;
      acc[2][0] += x2 * b.x; acc[2][1] += x2 * b.y; acc[2][2] += x2 * b.z; acc[2][3] += x2 * b.w;
      acc[3][0] += x3 * b.x; acc[3][1] += x3 * b.y; acc[3][2] += x3 * b.z; acc[3][3] += x3 * b.w;
    }
    __syncthreads();
  }

  const int cbase = tx * 4;
  const bool cok = cbase + 3 < NCLASS;   // tx <= 9
  float4 av_s = make_float4(0.f, 0.f, 0.f, 0.f);
  float4 av_d = make_float4(0.f, 0.f, 0.f, 0.f);
  if (cok) {
    av_s = *(const float4*)&asrc[cbase];
    av_d = *(const float4*)&adst[cbase];
  }

  #pragma unroll
  for (int i = 0; i < 4; ++i) {
    int r = row0 + ty * 4 + i;
    bool ok = r < M;
    float ps = acc[i][0] * av_s.x + acc[i][1] * av_s.y + acc[i][2] * av_s.z + acc[i][3] * av_s.w;
    float pd = acc[i][0] * av_d.x + acc[i][1] * av_d.y + acc[i][2] * av_d.z + acc[i][3] * av_d.w;
    #pragma unroll
    for (int m = 1; m < 16; m <<= 1) {
      ps += __shfl_xor(ps, m, 64);
      pd += __shfl_xor(pd, m, 64);
    }
    if (ok && cok) {
      ushort4 o;
      o.x = f2bf(acc[i][0]); o.y = f2bf(acc[i][1]);
      o.z = f2bf(acc[i][2]); o.w = f2bf(acc[i][3]);
      *(ushort4*)&h2b[(size_t)r * NCLASS + cbase] = o;
    }
    if (ok && tx == 0) { ssrc2[r] = ps; sdst2[r] = pd; }
  }
}

// ---------------- fused softmax + aggregation ----------------
// Batched edge weights + 8-deep payload-gather unroll (MLP).

__global__ __launch_bounds__(64) void agg1_kernel(const ushort* __restrict__ h1b,
    const float* __restrict__ s_src, const float* __restrict__ s_dst,
    const int* __restrict__ row_off, const int* __restrict__ edge_src,
    const float* __restrict__ b1, ushort* __restrict__ hrelu_b) {
  int v = blockIdx.x;
  int l = threadIdx.x;
  int head = l >> 4;
  int elane = l & 15;
  int c = l * 4;
  float sdv = s_dst[v * HEADS + head];

  // self-loop
  float wself = __expf(lrelu(s_src[v * HEADS + head] + sdv));
  ushort4 hv = *(const ushort4*)&h1b[(size_t)v * NHID + c];
  float4 acc = make_float4(wself * bf2f(hv.x), wself * bf2f(hv.y),
                           wself * bf2f(hv.z), wself * bf2f(hv.w));
  float zp = (elane == 0) ? wself : 0.f;

  int i = row_off[v], end = row_off[v + 1];
  for (; i < end; i += 16) {
    int cnt = end - i;
    if (cnt > 16) cnt = 16;
    bool val = elane < cnt;
    int u = edge_src[val ? (i + elane) : i];
    float wl = 0.f;
    if (val) wl = __expf(lrelu(s_src[u * HEADS + head] + sdv));
    zp += wl;

    int e = 0;
    for (; e + 7 < cnt; e += 8) {
      int uu[8];
      float ww[8];
      ushort4 rr8[8];
      #pragma unroll
      for (int q = 0; q < 8; ++q) {
        uu[q] = __shfl(u, e + q);
        ww[q] = __shfl(wl, (l & 48) | (e + q));
      }
      #pragma unroll
      for (int q = 0; q < 8; ++q)
        rr8[q] = *(const ushort4*)&h1b[(size_t)uu[q] * NHID + c];
      #pragma unroll
      for (int q = 0; q < 8; ++q) {
        acc.x += ww[q] * bf2f(rr8[q].x);
        acc.y += ww[q] * bf2f(rr8[q].y);
        acc.z += ww[q] * bf2f(rr8[q].z);
        acc.w += ww[q] * bf2f(rr8[q].w);
      }
    }
    for (; e + 3 < cnt; e += 4) {
      int u0 = __shfl(u, e + 0);
      int u1 = __shfl(u, e + 1);
      int u2 = __shfl(u, e + 2);
      int u3 = __shfl(u, e + 3);
      float w0 = __shfl(wl, (l & 48) | (e + 0));
      float w1 = __shfl(wl, (l & 48) | (e + 1));
      float w2 = __shfl(wl, (l & 48) | (e + 2));
      float w3 = __shfl(wl, (l & 48) | (e + 3));
      ushort4 r0 = *(const ushort4*)&h1b[(size_t)u0 * NHID + c];
      ushort4 r1 = *(const ushort4*)&h1b[(size_t)u1 * NHID + c];
      ushort4 r2 = *(const ushort4*)&h1b[(size_t)u2 * NHID + c];
      ushort4 r3 = *(const ushort4*)&h1b[(size_t)u3 * NHID + c];
      acc.x += w0 * bf2f(r0.x) + w1 * bf2f(r1.x) + w2 * bf2f(r2.x) + w3 * bf2f(r3.x);
      acc.y += w0 * bf2f(r0.y) + w1 * bf2f(r1.y) + w2 * bf2f(r2.y) + w3 * bf2f(r3.y);
      acc.z += w0 * bf2f(r0.z) + w1 * bf2f(r1.z) + w2 * bf2f(r2.z) + w3 * bf2f(r3.z);
      acc.w += w0 * bf2f(r0.w) + w1 * bf2f(r1.w) + w2 * bf2f(r2.w) + w3 * bf2f(r3.w);
    }
    for (; e < cnt; ++e) {
      int ue = __shfl(u, e);
      float we = __shfl(wl, (l & 48) | e);
      ushort4 ru = *(const ushort4*)&h1b[(size_t)ue * NHID + c];
      acc.x += we * bf2f(ru.x);
      acc.y += we * bf2f(ru.y);
      acc.z += we * bf2f(ru.z);
      acc.w += we * bf2f(ru.w);
    }
  }
  #pragma unroll
  for (int m = 1; m < 16; m <<= 1) zp += __shfl_xor(zp, m, 64);

  float inv = 1.f / (zp + EPS_Z);
  float4 bb = *(const float4*)&b1[c];
  ushort4 o;
  o.x = f2bf(fmaxf(acc.x * inv + bb.x, 0.f));
  o.y = f2bf(fmaxf(acc.y * inv + bb.y, 0.f));
  o.z = f2bf(fmaxf(acc.z * inv + bb.z, 0.f));
  o.w = f2bf(fmaxf(acc.w * inv + bb.w, 0.f));
  *(ushort4*)&hrelu_b[(size_t)v * NHID + c] = o;
}

// agg2: EB=64 (single head); 8-deep payload unroll.
__global__ __launch_bounds__(64) void agg2_kernel(const ushort* __restrict__ h2b,
    const float* __restrict__ s_src, const float* __restrict__ s_dst,
    const int* __restrict__ row_off, const int* __restrict__ edge_src,
    const float* __restrict__ b2, float* __restrict__ out) {
  int v = blockIdx.x;
  int l = threadIdx.x;
  bool act = l < NCLASS;
  float sdv = s_dst[v];

  float wself = __expf(lrelu(s_src[v] + sdv));
  float acc = act ? wself * bf2f(h2b[(size_t)v * NCLASS + l]) : 0.f;
  float zp = (l == 0) ? wself : 0.f;

  int i = row_off[v], end = row_off[v + 1];
  for (; i < end; i += 64) {
    int cnt = end - i;
    if (cnt > 64) cnt = 64;
    bool val = l < cnt;
    int u = edge_src[val ? (i + l) : i];
    float wl = 0.f;
    if (val) wl = __expf(lrelu(s_src[u] + sdv));
    zp += wl;

    int e = 0;
    for (; e + 7 < cnt; e += 8) {
      int uu[8];
      float ww[8];
      ushort pp[8];
      #pragma unroll
      for (int q = 0; q < 8; ++q) {
        uu[q] = __shfl(u, e + q);
        ww[q] = __shfl(wl, e + q);
      }
      #pragma unroll
      for (int q = 0; q < 8; ++q)
        pp[q] = act ? h2b[(size_t)uu[q] * NCLASS + l] : (ushort)0;
      if (act) {
        #pragma unroll
        for (int q = 0; q < 8; ++q) acc += ww[q] * bf2f(pp[q]);
      }
    }
    for (; e < cnt; ++e) {
      int ue = __shfl(u, e);
      float we = __shfl(wl, e);
      if (act) acc += we * bf2f(h2b[(size_t)ue * NCLASS + l]);
    }
  }
  #pragma unroll
  for (int m = 1; m < 64; m <<= 1) zp += __shfl_xor(zp, m, 64);

  if (act) out[(size_t)v * NCLASS + l] = acc / (zp + EPS_Z) + b2[l];
}

// ---------------- launch ----------------

extern "C" void kernel_launch(void* const* d_in, const int* in_sizes, int n_in,
                              void* d_out, int out_size, void* d_ws, size_t ws_size,
                              hipStream_t stream) {
  const float* x   = (const float*)d_in[0];
  const int*   adj = (const int*)d_in[1];
  const float* W1  = (const float*)d_in[2];
  const float* as1 = (const float*)d_in[3];
  const float* ad1 = (const float*)d_in[4];
  const float* b1  = (const float*)d_in[5];
  const float* W2  = (const float*)d_in[6];
  const float* as2 = (const float*)d_in[7];
  const float* ad2 = (const float*)d_in[8];
  const float* b2  = (const float*)d_in[9];
  float* out = (float*)d_out;

  const int N = in_sizes[0] / NFEAT;   // 50000
  const int E = in_sizes[1] / 2;       // 800000

  char* ws = (char*)d_ws;
  size_t off = 0;
  auto alloc = [&](size_t bytes) -> void* {
    void* p = ws + off;
    off = (off + bytes + 255) & ~(size_t)255;
    return p;
  };
  ushort* h1b    = (ushort*)alloc((size_t)N * NHID * 2);
  ushort* hrelub = (ushort*)alloc((size_t)N * NHID * 2);
  ushort* h2b    = (ushort*)alloc((size_t)N * NCLASS * 2);
  float* ssrc1   = (float*)alloc((size_t)N * HEADS * 4);
  float* sdst1   = (float*)alloc((size_t)N * HEADS * 4);
  float* ssrc2   = (float*)alloc((size_t)N * 4);
  float* sdst2   = (float*)alloc((size_t)N * 4);
  int* counts    = (int*)alloc((size_t)N * 4);
  int* cursor    = (int*)alloc((size_t)N * 4);
  int* row_off   = (int*)alloc((size_t)(N + 1) * 4);
  int* edge_src  = (int*)alloc((size_t)E * 4);
  int* excl      = (int*)alloc((size_t)N * 4);
  int* bsum      = (int*)alloc((size_t)1024 * 4);
  ushort* whp    = (ushort*)alloc((size_t)NFEAT * NHID * 2);
  (void)ws_size;

  const int* srcv = adj;
  const int* dstv = adj + E;
  const int nb = (N + 1023) / 1024;

  // W1 -> frag-major bf16
  wprep_kernel<<<256, 64, 0, stream>>>(W1, whp);

  // CSR by dst (parallel 3-phase scan)
  hipMemsetAsync(counts, 0, (size_t)N * 4, stream);
  count_kernel<<<(E + 255) / 256, 256, 0, stream>>>(dstv, E, counts);
  scan_a<<<nb, 1024, 0, stream>>>(counts, excl, bsum, N);
  scan_b<<<1, 1024, 0, stream>>>(bsum, nb);
  scan_c<<<(N + 255) / 256, 256, 0, stream>>>(excl, bsum, row_off, cursor, N, E);
  scatter_kernel<<<(E + 255) / 256, 256, 0, stream>>>(srcv, dstv, E, cursor, edge_src);

  // layer 1
  gemm1_mfma<<<(N + 63) / 64, 256, 0, stream>>>(x, whp, as1, ad1, h1b, ssrc1, sdst1, N);
  agg1_kernel<<<N, 64, 0, stream>>>(h1b, ssrc1, sdst1, row_off, edge_src, b1, hrelub);

  // layer 2
  gemm2_fused<<<(N + 63) / 64, 256, 0, stream>>>(hrelub, W2, as2, ad2, h2b, ssrc2, sdst2, N);
  agg2_kernel<<<N, 64, 0, stream>>>(h2b, ssrc2, sdst2, row_off, edge_src, b2, out);
}